// Round 4
// baseline (1920.213 us; speedup 1.0000x reference)
//
#include <hip/hip_runtime.h>
#include <hip/hip_bf16.h>
#include <math.h>
#include <stdint.h>

typedef unsigned short u16;
typedef __attribute__((ext_vector_type(8))) short bf16x8;
typedef __attribute__((ext_vector_type(4))) float f32x4;

__device__ __forceinline__ float b2f(u16 u) {
  union { float f; uint32_t i; } v; v.i = ((uint32_t)u) << 16; return v.f;
}
__device__ __forceinline__ u16 f2b(float f) {
  union { float f; uint32_t i; } v; v.f = f;
  uint32_t x = v.i;
  return (u16)((x + 0x7fffu + ((x >> 16) & 1u)) >> 16);
}

// async global->LDS, 16B per lane; LDS dest must be wave-uniform base + lane*16
__device__ __forceinline__ void gl_lds16(const u16* g, u16* l) {
  __builtin_amdgcn_global_load_lds(
      (const __attribute__((address_space(1))) void*)g,
      (__attribute__((address_space(3))) void*)l, 16, 0, 0);
}

// ---------------------------------------------------------------------------
// Weight transpose + fp32->bf16: in fp32 [K][N] -> out bf16 [N][K].
// ---------------------------------------------------------------------------
__global__ __launch_bounds__(256)
void transpose_w(const float* __restrict__ in, u16* __restrict__ out, int K, int N) {
  __shared__ float t[32][33];
  const int x = threadIdx.x & 31;
  const int y = threadIdx.x >> 5;         // 0..7
  const int n0 = blockIdx.x * 32;
  const int k0 = blockIdx.y * 32;
  #pragma unroll
  for (int yy = 0; yy < 32; yy += 8)
    t[y + yy][x] = in[(size_t)(k0 + y + yy) * N + n0 + x];
  __syncthreads();
  #pragma unroll
  for (int yy = 0; yy < 32; yy += 8)
    out[(size_t)(n0 + y + yy) * K + k0 + x] = f2b(t[x][y + yy]);
}

// ---------------------------------------------------------------------------
// Cast rel-pos tables fp32[27][64] -> bf16.
// ---------------------------------------------------------------------------
__global__ __launch_bounds__(256)
void rel_cast(const float* __restrict__ rph, const float* __restrict__ rpw,
              u16* __restrict__ RHB, u16* __restrict__ RWB)
{
  const int i = blockIdx.x * 256 + threadIdx.x;
  if (i < 27 * 64) { RHB[i] = f2b(rph[i]); RWB[i] = f2b(rpw[i]); }
}

// ---------------------------------------------------------------------------
// LayerNorm over C=768 (fp32 in, bf16 out), one wave per row, raster rows.
// ---------------------------------------------------------------------------
__global__ __launch_bounds__(256)
void ln_f32(const float* __restrict__ xin, const float* __restrict__ g,
            const float* __restrict__ b, u16* __restrict__ out)
{
  const int R = blockIdx.x * 4 + (threadIdx.x >> 6);   // 0..32767
  const int lane = threadIdx.x & 63;
  const float* p = xin + (size_t)R * 768 + lane * 12;
  float v[12];
  float4 a0 = *(const float4*)(p);
  float4 a1 = *(const float4*)(p + 4);
  float4 a2 = *(const float4*)(p + 8);
  v[0]=a0.x; v[1]=a0.y; v[2]=a0.z;  v[3]=a0.w;
  v[4]=a1.x; v[5]=a1.y; v[6]=a1.z;  v[7]=a1.w;
  v[8]=a2.x; v[9]=a2.y; v[10]=a2.z; v[11]=a2.w;
  float sum = 0.f, sq = 0.f;
  #pragma unroll
  for (int i = 0; i < 12; ++i) { sum += v[i]; sq += v[i] * v[i]; }
  #pragma unroll
  for (int m = 1; m < 64; m <<= 1) { sum += __shfl_xor(sum, m); sq += __shfl_xor(sq, m); }
  const float mu  = sum * (1.0f / 768.0f);
  const float var = sq * (1.0f / 768.0f) - mu * mu;
  const float rs  = rsqrtf(var + 1e-6f);
  u16 o[12];
  #pragma unroll
  for (int i = 0; i < 12; ++i)
    o[i] = f2b((v[i] - mu) * rs * g[lane * 12 + i] + b[lane * 12 + i]);
  u16* q = out + (size_t)R * 768 + lane * 12;
  *(ushort4*)(q)     = make_ushort4(o[0], o[1], o[2],  o[3]);
  *(ushort4*)(q + 4) = make_ushort4(o[4], o[5], o[6],  o[7]);
  *(ushort4*)(q + 8) = make_ushort4(o[8], o[9], o[10], o[11]);
}

// ---------------------------------------------------------------------------
// Pad-row fill for Q/K/V^T: padded window tokens (gh>=64 || gw>=64) have
// h==0 after the reference's post-LN zero-pad, so qkv = bias exactly.
// ---------------------------------------------------------------------------
__global__ __launch_bounds__(256)
void qkv_padfill(const float* __restrict__ qkv_b,
                 u16* __restrict__ Qb, u16* __restrict__ Kb, u16* __restrict__ Vtb)
{
  const int R = blockIdx.x * 4 + (threadIdx.x >> 6);   // 0..39199 = win*196+n
  const int lane = threadIdx.x & 63;
  const int win = R / 196, n = R - win * 196;
  const int r25 = win % 25;
  const int wh = r25 / 5, ww = r25 - wh * 5;
  const int ii = n / 14,  jj = n - ii * 14;
  const int gh = wh * 14 + ii, gw = ww * 14 + jj;
  if (gh < 64 && gw < 64) return;   // interior handled by the QKV GEMM
  #pragma unroll
  for (int head = 0; head < 12; ++head) {
    const size_t bh = (size_t)(win * 12 + head);
    Qb[(bh * 196 + n) * 64 + lane]  = f2b(qkv_b[head * 64 + lane]);
    Kb[(bh * 196 + n) * 64 + lane]  = f2b(qkv_b[768 + head * 64 + lane] * 0.125f);
    Vtb[(bh * 64 + lane) * 224 + n] = f2b(qkv_b[1536 + head * 64 + lane]);
  }
}

// ---------------------------------------------------------------------------
// GEMM: C[M,N] = A[M,K] @ B[K,N] (+fp32 bias, fused epilogue).  A,BT bf16.
// 128x128 tile, BK=32, 256 thr = 4 waves, each wave 64x64 via 4x4 tiles of
// mfma_f32_16x16x32_bf16.  Staging via global_load_lds (16B/lane).
// XCD-chunk swizzle: each XCD sweeps a contiguous m-range, n fastest, so the
// A panel stays L2-resident across n-passes (all grids have nwg % 8 == 0).
// Epilogue stores are nontemporal (streamed, never re-read soon at L2/L3
// granularity); residual reads are nontemporal loads.
// EPI: 0 = QKV scatter (out0=Q bf16, out1=K*0.125 bf16, out2=V^T bf16 s224)
//      1 = +bias, +extra(fp32 residual) -> fp32 out0   (proj & mlp2)
//      2 = +bias, sigmoid-form GELU -> bf16 out0 [M,3072]  (mlp1)
// M must be a multiple of 128 (all launches comply).
// ---------------------------------------------------------------------------
template<int EPI>
__global__ __launch_bounds__(256)
void gemm_bt(const u16* __restrict__ A, const u16* __restrict__ BT,
             int M, int N, int K,
             const float* __restrict__ bias,
             void* __restrict__ out0, u16* __restrict__ out1, u16* __restrict__ out2,
             const float* __restrict__ extra)
{
  __shared__ __align__(16) u16 As[128 * 32];
  __shared__ __align__(16) u16 Bs[128 * 32];
  const int tid  = threadIdx.x;
  const int lane = tid & 63;
  const int wave = tid >> 6;

  // XCD-chunk swizzle (bijective; nwg % 8 == 0 for every launch)
  const int nwg = gridDim.x * gridDim.y;
  const int lid = blockIdx.y * gridDim.x + blockIdx.x;   // dispatch-linear (x fastest)
  const int nl  = (lid & 7) * (nwg >> 3) + (lid >> 3);
  const int bx  = nl / gridDim.y;          // m-tile
  const int by  = nl - bx * gridDim.y;     // n-tile (fastest within an XCD chunk)
  const int m0 = bx * 128;
  const int n0 = by * 128;

  const int wm = (wave >> 1) << 6;
  const int wn = (wave & 1) << 6;
  const int cl = lane & 15;
  const int q4 = lane >> 4;

  f32x4 acc[4][4];
  #pragma unroll
  for (int i = 0; i < 4; ++i)
    #pragma unroll
    for (int j = 0; j < 4; ++j) acc[i][j] = f32x4{0.f, 0.f, 0.f, 0.f};

  const int sr = tid >> 2;            // 0..63
  const int sk = (tid & 3) << 3;      // 0,8,16,24
  const u16* ag0 = A  + (size_t)(m0 + sr) * K + sk;
  const u16* ag1 = A  + (size_t)(m0 + 64 + sr) * K + sk;
  const u16* bg0 = BT + (size_t)(n0 + sr) * K + sk;
  const u16* bg1 = BT + (size_t)(n0 + 64 + sr) * K + sk;

  for (int k0 = 0; k0 < K; k0 += 32) {
    __syncthreads();   // previous iteration's fragment reads complete
    gl_lds16(ag0 + k0, &As[tid * 8]);
    gl_lds16(ag1 + k0, &As[tid * 8 + 2048]);
    gl_lds16(bg0 + k0, &Bs[tid * 8]);
    gl_lds16(bg1 + k0, &Bs[tid * 8 + 2048]);
    __syncthreads();   // compiler drains vmcnt(0) before barrier: tile visible
    bf16x8 af[4], bfv[4];
    #pragma unroll
    for (int i = 0; i < 4; ++i) af[i]  = *(const bf16x8*)&As[(wm + i * 16 + cl) * 32 + q4 * 8];
    #pragma unroll
    for (int i = 0; i < 4; ++i) bfv[i] = *(const bf16x8*)&Bs[(wn + i * 16 + cl) * 32 + q4 * 8];
    #pragma unroll
    for (int i = 0; i < 4; ++i)
      #pragma unroll
      for (int j = 0; j < 4; ++j)
        acc[i][j] = __builtin_amdgcn_mfma_f32_16x16x32_bf16(af[i], bfv[j], acc[i][j], 0, 0, 0);
  }

  #pragma unroll
  for (int mt = 0; mt < 4; ++mt) {
    int rowW[4], rowN[4];
    if (EPI == 0) {
      // hoist raster->window mapping out of the nt loop (depends on grow only)
      #pragma unroll
      for (int i = 0; i < 4; ++i) {
        const int grow = m0 + wm + mt * 16 + q4 * 4 + i;
        const int bb = grow >> 12, rem = grow & 4095;
        const int gh = rem >> 6, gw = rem & 63;
        const int wh = gh / 14, ii = gh - wh * 14;
        const int ww = gw / 14, jj = gw - ww * 14;
        rowW[i] = (bb * 25 + wh * 5 + ww) * 12;   // win*12
        rowN[i] = ii * 14 + jj;                   // n
      }
    }
    #pragma unroll
    for (int nt = 0; nt < 4; ++nt) {
      const int gcol = n0 + wn + nt * 16 + cl;
      const float bval = bias[gcol];
      if (EPI == 0) {
        const int s = (gcol >= 1536) ? 2 : (gcol >= 768 ? 1 : 0);
        const int rem2 = gcol - s * 768;
        const int head = rem2 >> 6, hd = rem2 & 63;
        #pragma unroll
        for (int i = 0; i < 4; ++i) {
          const float v = acc[mt][nt][i] + bval;
          const size_t bh = (size_t)(rowW[i] + head);
          if (s == 0)
            __builtin_nontemporal_store(f2b(v), &((u16*)out0)[(bh * 196 + rowN[i]) * 64 + hd]);
          else if (s == 1)
            __builtin_nontemporal_store(f2b(v * 0.125f), &out1[(bh * 196 + rowN[i]) * 64 + hd]); // fold SCALE into K
          else
            __builtin_nontemporal_store(f2b(v), &out2[(bh * 64 + hd) * 224 + rowN[i]]);          // V^T, stride 224
        }
      } else if (EPI == 1) {
        #pragma unroll
        for (int i = 0; i < 4; ++i) {
          const int grow = m0 + wm + mt * 16 + q4 * 4 + i;
          const size_t idx = (size_t)grow * 768 + gcol;
          const float v = acc[mt][nt][i] + bval + __builtin_nontemporal_load(&extra[idx]);
          __builtin_nontemporal_store(v, &((float*)out0)[idx]);
        }
      } else {
        #pragma unroll
        for (int i = 0; i < 4; ++i) {
          const int grow = m0 + wm + mt * 16 + q4 * 4 + i;
          const float v = acc[mt][nt][i] + bval;
          // gelu(v) = v * sigmoid(1.5957691216 v (1 + 0.044715 v^2)); |err|<~4e-4
          const float u2 = v * (1.5957691216f + 0.0713548163f * v * v);
          const float gl = v / (1.0f + __expf(-u2));
          __builtin_nontemporal_store(f2b(gl), &((u16*)out0)[(size_t)grow * 3072 + gcol]);
        }
      }
    }
  }
}

// ---------------------------------------------------------------------------
// Windowed attention, one workgroup per (win, head).  N=196 tokens, HD=64.
// Phase 0: rel-pos bias via structure-exploiting MFMA — group q-rows by
// ii (for rel_h) / jj (for rel_w): one 16x16x64 tile per group, 28 tiles
// total -> MhAll/MwAll[196][14] bf16 in LDS.
// Per 32-row chunk: 26 score tiles (bias folded at write) -> no-max softmax
// (unnormalized e bf16, 1/sum folded into PV epilogue) -> PV + raster write.
// Ps (u16, stride 232) aliases the Ss f32 buffer; barrier separates the
// softmax read and write phases.  LDS ~37 KB -> 4 blocks/CU.
// ---------------------------------------------------------------------------
__global__ __launch_bounds__(256)
void attn_kernel(const u16* __restrict__ Qb, const u16* __restrict__ Kb,
                 const u16* __restrict__ Vtb,
                 const u16* __restrict__ RHB, const u16* __restrict__ RWB,
                 u16* __restrict__ outO)
{
  __shared__ __align__(16) float Ss[32 * 201];   // Ps (u16, stride 232) aliases base
  __shared__ u16 MhAll[196 * 14];
  __shared__ u16 MwAll[196 * 14];
  __shared__ float Sinv[32];
  u16* Ps = (u16*)Ss;

  const int tid  = threadIdx.x;
  const int lane = tid & 63;
  const int wave = tid >> 6;
  const int cl = lane & 15;
  const int q4 = lane >> 4;
  const int bh = blockIdx.x;
  const int win = bh / 12, head = bh - win * 12;
  const int bb = win / 25, r25 = win - bb * 25;
  const int wwh = r25 / 5, www = r25 - wwh * 5;

  const u16* Qbh = Qb  + (size_t)bh * 196 * 64;
  const u16* Kbh = Kb  + (size_t)bh * 196 * 64;
  const u16* Vbh = Vtb + (size_t)bh * 64 * 224;

  // ---- Phase 0: MhAll/MwAll via 28 tiles (rel_h grouped by ii, rel_w by jj)
  for (int t = wave; t < 28; t += 4) {
    const int isW = t >= 14;
    const int grp = isW ? t - 14 : t;               // ii (rel_h) or jj (rel_w)
    const int qrow = isW ? cl * 14 + grp : grp * 14 + cl;  // A row cl -> token
    int trow = grp - cl + 13; trow = trow < 0 ? 0 : trow;  // B row cl -> table row
    const u16* TB = isW ? RWB : RHB;
    f32x4 acc = f32x4{0.f, 0.f, 0.f, 0.f};
    #pragma unroll
    for (int ks = 0; ks < 2; ++ks) {
      bf16x8 a  = *(const bf16x8*)(Qbh + (size_t)qrow * 64 + ks * 32 + q4 * 8);
      bf16x8 bv = *(const bf16x8*)(TB + (size_t)trow * 64 + ks * 32 + q4 * 8);
      acc = __builtin_amdgcn_mfma_f32_16x16x32_bf16(a, bv, acc, 0, 0, 0);
    }
    if (cl < 14) {
      #pragma unroll
      for (int i = 0; i < 4; ++i) {
        const int r = q4 * 4 + i;                   // A-row index = group member
        if (r < 14) {
          if (isW) MwAll[(r * 14 + grp) * 14 + cl] = f2b(acc[i]);   // q = r*14+jj
          else     MhAll[(grp * 14 + r) * 14 + cl] = f2b(acc[i]);   // q = ii*14+r
        }
      }
    }
  }
  __syncthreads();

  for (int c = 0; c < 7; ++c) {
    const int qbase = c * 32;
    // hoist this chunk's Q fragments (rows >=196: finite garbage, discarded)
    bf16x8 afr[2][2];
    #pragma unroll
    for (int mt = 0; mt < 2; ++mt)
      #pragma unroll
      for (int ks = 0; ks < 2; ++ks)
        afr[mt][ks] = *(const bf16x8*)(Qbh + (size_t)(qbase + mt * 16 + cl) * 64 + ks * 32 + q4 * 8);

    // ---- score tiles, rel bias folded at write
    for (int t = wave; t < 26; t += 4) {
      const int mt = t / 13, nt = t - mt * 13;
      const int col = nt * 16 + cl;
      f32x4 acc = f32x4{0.f, 0.f, 0.f, 0.f};
      #pragma unroll
      for (int ks = 0; ks < 2; ++ks) {
        bf16x8 bv = *(const bf16x8*)(Kbh + (size_t)col * 64 + ks * 32 + q4 * 8);
        acc = __builtin_amdgcn_mfma_f32_16x16x32_bf16(afr[mt][ks], bv, acc, 0, 0, 0);
      }
      if (col < 196) {
        const int kh = col / 14, kw = col - kh * 14;
        #pragma unroll
        for (int i = 0; i < 4; ++i) {
          const int r = mt * 16 + q4 * 4 + i;
          const int gq = qbase + r;
          float bias = 0.f;
          if (gq < 196) bias = b2f(MhAll[gq * 14 + kh]) + b2f(MwAll[gq * 14 + kw]);
          Ss[r * 201 + col] = acc[i] + bias;
        }
      }
    }
    __syncthreads();                                    // B1: scores visible

    // ---- softmax read: no max-subtraction (|S| bounded), clamp vs garbage rows
    const int r = wave * 8 + (lane >> 3);
    const int s = lane & 7;
    float e[25];
    float sum = 0.f;
    #pragma unroll
    for (int k = 0; k < 25; ++k) {
      const int col = s + 8 * k;
      float ex = 0.f;
      if (col < 196) ex = __expf(fminf(Ss[r * 201 + col], 60.f));
      e[k] = ex;
      sum += ex;
    }
    sum += __shfl_xor(sum, 1);
    sum += __shfl_xor(sum, 2);
    sum += __shfl_xor(sum, 4);
    if (s == 0) Sinv[r] = 1.0f / sum;
    __syncthreads();                                    // B2: Ss reads done, may clobber

    // ---- write unnormalized e as bf16 into Ps (aliases Ss); zero pad cols
    #pragma unroll
    for (int k = 0; k < 25; ++k) {
      const int col = s + 8 * k;                        // <= 199
      Ps[r * 232 + col] = (col < 196) ? f2b(e[k]) : (u16)0;
    }
    for (int z = tid; z < 384; z += 256) {              // cols 200..223 -> 0
      const int rr = z / 12, m = z - rr * 12;
      *(uint32_t*)&Ps[rr * 232 + 200 + 2 * m] = 0;
    }
    __syncthreads();                                    // B3: Ps ready

    // ---- O = P @ V, normalize by Sinv in epilogue; raster write
    {
      const int hd = wave * 16 + cl;
      f32x4 acc0 = f32x4{0.f, 0.f, 0.f, 0.f};
      f32x4 acc1 = f32x4{0.f, 0.f, 0.f, 0.f};
      #pragma unroll
      for (int ks = 0; ks < 7; ++ks) {
        bf16x8 bv = *(const bf16x8*)(Vbh + (size_t)hd * 224 + ks * 32 + q4 * 8);
        bf16x8 a0 = *(const bf16x8*)&Ps[(cl)      * 232 + ks * 32 + q4 * 8];
        bf16x8 a1 = *(const bf16x8*)&Ps[(16 + cl) * 232 + ks * 32 + q4 * 8];
        acc0 = __builtin_amdgcn_mfma_f32_16x16x32_bf16(a0, bv, acc0, 0, 0, 0);
        acc1 = __builtin_amdgcn_mfma_f32_16x16x32_bf16(a1, bv, acc1, 0, 0, 0);
      }
      #pragma unroll
      for (int i = 0; i < 4; ++i) {
        #pragma unroll
        for (int half = 0; half < 2; ++half) {
          const int q = qbase + half * 16 + q4 * 4 + i;
          if (q < 196) {
            const float av = (half ? acc1[i] : acc0[i]) * Sinv[half * 16 + q4 * 4 + i];
            const int ii = q / 14, jj = q - ii * 14;
            const int gh = wwh * 14 + ii, gw = www * 14 + jj;
            if (gh < 64 && gw < 64)
              outO[(((size_t)bb * 64 + gh) * 64 + gw) * 768 + head * 64 + hd] = f2b(av);
          }
        }
      }
    }
    __syncthreads();                                    // B4: Ps consumed
  }
}

// ---------------------------------------------------------------------------
extern "C" void kernel_launch(void* const* d_in, const int* in_sizes, int n_in,
                              void* d_out, int out_size, void* d_ws, size_t ws_size,
                              hipStream_t stream)
{
  (void)in_sizes; (void)n_in; (void)out_size; (void)ws_size;
  const float* x      = (const float*)d_in[0];
  const float* ln1_g  = (const float*)d_in[1];
  const float* ln1_b  = (const float*)d_in[2];
  const float* qkv_w  = (const float*)d_in[3];
  const float* qkv_b  = (const float*)d_in[4];
  const float* proj_w = (const float*)d_in[5];
  const float* proj_b = (const float*)d_in[6];
  const float* rph    = (const float*)d_in[7];
  const float* rpw    = (const float*)d_in[8];
  const float* ln2_g  = (const float*)d_in[9];
  const float* ln2_b  = (const float*)d_in[10];
  const float* lin1_w = (const float*)d_in[11];
  const float* lin1_b = (const float*)d_in[12];
  const float* lin2_w = (const float*)d_in[13];
  const float* lin2_b = (const float*)d_in[14];
  float* outF = (float*)d_out;

  char* ws = (char*)d_ws;
  size_t off = 0;
  auto allocB = [&](size_t bytes) -> char* {
    char* p = ws + off;
    off += (bytes + 255) & ~(size_t)255;
    return p;
  };
  u16* qkvT  = (u16*)allocB((size_t)2304 * 768 * 2);
  u16* projT = (u16*)allocB((size_t)768 * 768 * 2);
  u16* lin1T = (u16*)allocB((size_t)3072 * 768 * 2);
  u16* lin2T = (u16*)allocB((size_t)768 * 3072 * 2);
  u16* RHB   = (u16*)allocB((size_t)(27 * 64 + 64) * 2);
  u16* RWB   = (u16*)allocB((size_t)(27 * 64 + 64) * 2);
  u16* xn    = (u16*)allocB((size_t)32768 * 768 * 2);   // ln1-out -> attnO -> ln2-out
  char* region = allocB((size_t)201326592);             // Q|K|Vt, later hbuf+mid
  u16* Qb   = (u16*)region;                             // 30,105,600 elems
  u16* Kb   = Qb + (size_t)30105600;                    // 30,105,600 elems
  u16* Vtb  = Kb + (size_t)30105600;                    // 34,406,400 elems (2400*64*224)
  float* hbuf = (float*)region;                         // 32768*768 fp32 = 100,663,296 B
  u16* midQ = (u16*)(region + (size_t)100663296);       // 16384*3072 bf16 = 100,663,296 B
  // lifetimes: Q/K/V dead before proj writes hbuf; hbuf/midQ disjoint ranges.

  dim3 blk(256);
  transpose_w<<<dim3(72, 24), blk, 0, stream>>>(qkv_w,  qkvT, 768, 2304);
  transpose_w<<<dim3(24, 24), blk, 0, stream>>>(proj_w, projT, 768, 768);
  transpose_w<<<dim3(96, 24), blk, 0, stream>>>(lin1_w, lin1T, 768, 3072);
  transpose_w<<<dim3(24, 96), blk, 0, stream>>>(lin2_w, lin2T, 3072, 768);
  rel_cast<<<7, blk, 0, stream>>>(rph, rpw, RHB, RWB);

  // LN1 (raster rows) -> xn bf16
  ln_f32<<<8192, blk, 0, stream>>>(x, ln1_g, ln1_b, xn);

  // QKV projection, raster M, scatter epilogue (K pre-scaled, V^T stride 224)
  gemm_bt<0><<<dim3(256, 18), blk, 0, stream>>>(xn, qkvT, 32768, 2304, 768,
                                                qkv_b, Qb, Kb, Vtb, nullptr);
  // pad-token rows of Q/K/V = bias exactly
  qkv_padfill<<<9800, blk, 0, stream>>>(qkv_b, Qb, Kb, Vtb);

  // windowed attention -> attnO (= xn, raster, bf16)
  attn_kernel<<<2400, blk, 0, stream>>>(Qb, Kb, Vtb, RHB, RWB, xn);

  // proj + residual(x) -> hbuf fp32
  gemm_bt<1><<<dim3(256, 6), blk, 0, stream>>>(xn, projT, 32768, 768, 768,
                                               proj_b, hbuf, nullptr, nullptr, x);

  // LN2 -> xn bf16
  ln_f32<<<8192, blk, 0, stream>>>(hbuf, ln2_g, ln2_b, xn);

  // MLP in 2 M-passes of 16384 rows (mid half fits beside hbuf);
  // mlp2 grid 768 blocks (3/CU) vs 384 at 4-pass — occupancy fix.
  for (int pass = 0; pass < 2; ++pass) {
    const size_t ro = (size_t)pass * 16384;
    gemm_bt<2><<<dim3(128, 24), blk, 0, stream>>>(xn + ro * 768, lin1T, 16384, 3072, 768,
                                                  lin1_b, midQ, nullptr, nullptr, nullptr);
    gemm_bt<1><<<dim3(128, 6), blk, 0, stream>>>(midQ, lin2T, 16384, 768, 3072,
                                                 lin2_b, outF + ro * 768, nullptr, nullptr,
                                                 hbuf + ro * 768);
  }
}

// Round 5
// 1470.344 us; speedup vs baseline: 1.3060x; 1.3060x over previous
//
#include <hip/hip_runtime.h>
#include <hip/hip_bf16.h>
#include <math.h>
#include <stdint.h>

typedef unsigned short u16;
typedef __attribute__((ext_vector_type(8))) short bf16x8;
typedef __attribute__((ext_vector_type(4))) float f32x4;

__device__ __forceinline__ float b2f(u16 u) {
  union { float f; uint32_t i; } v; v.i = ((uint32_t)u) << 16; return v.f;
}
__device__ __forceinline__ u16 f2b(float f) {
  union { float f; uint32_t i; } v; v.f = f;
  uint32_t x = v.i;
  return (u16)((x + 0x7fffu + ((x >> 16) & 1u)) >> 16);
}

// async global->LDS, 16B per lane; LDS dest must be wave-uniform base + lane*16
__device__ __forceinline__ void gl_lds16(const u16* g, u16* l) {
  __builtin_amdgcn_global_load_lds(
      (const __attribute__((address_space(1))) void*)g,
      (__attribute__((address_space(3))) void*)l, 16, 0, 0);
}

// ---------------------------------------------------------------------------
// Weight transpose + fp32->bf16: in fp32 [K][N] -> out bf16 [N][K].
// ---------------------------------------------------------------------------
__global__ __launch_bounds__(256)
void transpose_w(const float* __restrict__ in, u16* __restrict__ out, int K, int N) {
  __shared__ float t[32][33];
  const int x = threadIdx.x & 31;
  const int y = threadIdx.x >> 5;         // 0..7
  const int n0 = blockIdx.x * 32;
  const int k0 = blockIdx.y * 32;
  #pragma unroll
  for (int yy = 0; yy < 32; yy += 8)
    t[y + yy][x] = in[(size_t)(k0 + y + yy) * N + n0 + x];
  __syncthreads();
  #pragma unroll
  for (int yy = 0; yy < 32; yy += 8)
    out[(size_t)(n0 + y + yy) * K + k0 + x] = f2b(t[x][y + yy]);
}

// ---------------------------------------------------------------------------
// Cast rel-pos tables fp32[27][64] -> bf16.
// ---------------------------------------------------------------------------
__global__ __launch_bounds__(256)
void rel_cast(const float* __restrict__ rph, const float* __restrict__ rpw,
              u16* __restrict__ RHB, u16* __restrict__ RWB)
{
  const int i = blockIdx.x * 256 + threadIdx.x;
  if (i < 27 * 64) { RHB[i] = f2b(rph[i]); RWB[i] = f2b(rpw[i]); }
}

// ---------------------------------------------------------------------------
// LayerNorm over C=768 (fp32 in, bf16 out), one wave per row, raster rows.
// ---------------------------------------------------------------------------
__global__ __launch_bounds__(256)
void ln_f32(const float* __restrict__ xin, const float* __restrict__ g,
            const float* __restrict__ b, u16* __restrict__ out)
{
  const int R = blockIdx.x * 4 + (threadIdx.x >> 6);   // 0..32767
  const int lane = threadIdx.x & 63;
  const float* p = xin + (size_t)R * 768 + lane * 12;
  float v[12];
  float4 a0 = *(const float4*)(p);
  float4 a1 = *(const float4*)(p + 4);
  float4 a2 = *(const float4*)(p + 8);
  v[0]=a0.x; v[1]=a0.y; v[2]=a0.z;  v[3]=a0.w;
  v[4]=a1.x; v[5]=a1.y; v[6]=a1.z;  v[7]=a1.w;
  v[8]=a2.x; v[9]=a2.y; v[10]=a2.z; v[11]=a2.w;
  float sum = 0.f, sq = 0.f;
  #pragma unroll
  for (int i = 0; i < 12; ++i) { sum += v[i]; sq += v[i] * v[i]; }
  #pragma unroll
  for (int m = 1; m < 64; m <<= 1) { sum += __shfl_xor(sum, m); sq += __shfl_xor(sq, m); }
  const float mu  = sum * (1.0f / 768.0f);
  const float var = sq * (1.0f / 768.0f) - mu * mu;
  const float rs  = rsqrtf(var + 1e-6f);
  u16 o[12];
  #pragma unroll
  for (int i = 0; i < 12; ++i)
    o[i] = f2b((v[i] - mu) * rs * g[lane * 12 + i] + b[lane * 12 + i]);
  u16* q = out + (size_t)R * 768 + lane * 12;
  *(ushort4*)(q)     = make_ushort4(o[0], o[1], o[2],  o[3]);
  *(ushort4*)(q + 4) = make_ushort4(o[4], o[5], o[6],  o[7]);
  *(ushort4*)(q + 8) = make_ushort4(o[8], o[9], o[10], o[11]);
}

// ---------------------------------------------------------------------------
// Pad-row fill for Q/K/V^T: padded window tokens (gh>=64 || gw>=64) have
// h==0 after the reference's post-LN zero-pad, so qkv = bias exactly.
// ---------------------------------------------------------------------------
__global__ __launch_bounds__(256)
void qkv_padfill(const float* __restrict__ qkv_b,
                 u16* __restrict__ Qb, u16* __restrict__ Kb, u16* __restrict__ Vtb)
{
  const int R = blockIdx.x * 4 + (threadIdx.x >> 6);   // 0..39199 = win*196+n
  const int lane = threadIdx.x & 63;
  const int win = R / 196, n = R - win * 196;
  const int r25 = win % 25;
  const int wh = r25 / 5, ww = r25 - wh * 5;
  const int ii = n / 14,  jj = n - ii * 14;
  const int gh = wh * 14 + ii, gw = ww * 14 + jj;
  if (gh < 64 && gw < 64) return;   // interior handled by the QKV GEMM
  #pragma unroll
  for (int head = 0; head < 12; ++head) {
    const size_t bh = (size_t)(win * 12 + head);
    Qb[(bh * 196 + n) * 64 + lane]  = f2b(qkv_b[head * 64 + lane]);
    Kb[(bh * 196 + n) * 64 + lane]  = f2b(qkv_b[768 + head * 64 + lane] * 0.125f);
    Vtb[(bh * 64 + lane) * 224 + n] = f2b(qkv_b[1536 + head * 64 + lane]);
  }
}

// ---------------------------------------------------------------------------
// GEMM: C[M,N] = A[M,K] @ B[K,N] (+fp32 bias, fused epilogue).  A,BT bf16.
// 128x128 tile, BK=32, 256 thr = 4 waves, each wave 64x64 via 4x4 tiles of
// mfma_f32_16x16x32_bf16.  Staging via global_load_lds (16B/lane).
// XCD-chunk swizzle: each XCD sweeps a contiguous m-range, n fastest, so the
// A panel stays L2-resident across n-passes (all grids have nwg % 8 == 0).
// NOTE: epilogue stores are PLAIN (L2-coalesced).  Nontemporal stores were
// tried (r4) and caused 3.6x HBM write amplification on the scattered
// epilogues (V^T 2B stores at 448B lane stride) — L2 write-combining is
// essential here.
// EPI: 0 = QKV scatter (out0=Q bf16, out1=K*0.125 bf16, out2=V^T bf16 s224)
//      1 = +bias, +extra(fp32 residual) -> fp32 out0   (proj & mlp2)
//      2 = +bias, sigmoid-form GELU -> bf16 out0 [M,3072]  (mlp1)
// M must be a multiple of 128 (all launches comply).
// ---------------------------------------------------------------------------
template<int EPI>
__global__ __launch_bounds__(256)
void gemm_bt(const u16* __restrict__ A, const u16* __restrict__ BT,
             int M, int N, int K,
             const float* __restrict__ bias,
             void* __restrict__ out0, u16* __restrict__ out1, u16* __restrict__ out2,
             const float* __restrict__ extra)
{
  __shared__ __align__(16) u16 As[128 * 32];
  __shared__ __align__(16) u16 Bs[128 * 32];
  const int tid  = threadIdx.x;
  const int lane = tid & 63;
  const int wave = tid >> 6;

  // XCD-chunk swizzle (bijective; nwg % 8 == 0 for every launch)
  const int nwg = gridDim.x * gridDim.y;
  const int lid = blockIdx.y * gridDim.x + blockIdx.x;   // dispatch-linear (x fastest)
  const int nl  = (lid & 7) * (nwg >> 3) + (lid >> 3);
  const int bx  = nl / gridDim.y;          // m-tile
  const int by  = nl - bx * gridDim.y;     // n-tile (fastest within an XCD chunk)
  const int m0 = bx * 128;
  const int n0 = by * 128;

  const int wm = (wave >> 1) << 6;
  const int wn = (wave & 1) << 6;
  const int cl = lane & 15;
  const int q4 = lane >> 4;

  f32x4 acc[4][4];
  #pragma unroll
  for (int i = 0; i < 4; ++i)
    #pragma unroll
    for (int j = 0; j < 4; ++j) acc[i][j] = f32x4{0.f, 0.f, 0.f, 0.f};

  const int sr = tid >> 2;            // 0..63
  const int sk = (tid & 3) << 3;      // 0,8,16,24
  const u16* ag0 = A  + (size_t)(m0 + sr) * K + sk;
  const u16* ag1 = A  + (size_t)(m0 + 64 + sr) * K + sk;
  const u16* bg0 = BT + (size_t)(n0 + sr) * K + sk;
  const u16* bg1 = BT + (size_t)(n0 + 64 + sr) * K + sk;

  for (int k0 = 0; k0 < K; k0 += 32) {
    __syncthreads();   // previous iteration's fragment reads complete
    gl_lds16(ag0 + k0, &As[tid * 8]);
    gl_lds16(ag1 + k0, &As[tid * 8 + 2048]);
    gl_lds16(bg0 + k0, &Bs[tid * 8]);
    gl_lds16(bg1 + k0, &Bs[tid * 8 + 2048]);
    __syncthreads();   // compiler drains vmcnt(0) before barrier: tile visible
    bf16x8 af[4], bfv[4];
    #pragma unroll
    for (int i = 0; i < 4; ++i) af[i]  = *(const bf16x8*)&As[(wm + i * 16 + cl) * 32 + q4 * 8];
    #pragma unroll
    for (int i = 0; i < 4; ++i) bfv[i] = *(const bf16x8*)&Bs[(wn + i * 16 + cl) * 32 + q4 * 8];
    #pragma unroll
    for (int i = 0; i < 4; ++i)
      #pragma unroll
      for (int j = 0; j < 4; ++j)
        acc[i][j] = __builtin_amdgcn_mfma_f32_16x16x32_bf16(af[i], bfv[j], acc[i][j], 0, 0, 0);
  }

  #pragma unroll
  for (int mt = 0; mt < 4; ++mt) {
    int rowW[4], rowN[4];
    if (EPI == 0) {
      // hoist raster->window mapping out of the nt loop (depends on grow only)
      #pragma unroll
      for (int i = 0; i < 4; ++i) {
        const int grow = m0 + wm + mt * 16 + q4 * 4 + i;
        const int bb = grow >> 12, rem = grow & 4095;
        const int gh = rem >> 6, gw = rem & 63;
        const int wh = gh / 14, ii = gh - wh * 14;
        const int ww = gw / 14, jj = gw - ww * 14;
        rowW[i] = (bb * 25 + wh * 5 + ww) * 12;   // win*12
        rowN[i] = ii * 14 + jj;                   // n
      }
    }
    #pragma unroll
    for (int nt = 0; nt < 4; ++nt) {
      const int gcol = n0 + wn + nt * 16 + cl;
      const float bval = bias[gcol];
      if (EPI == 0) {
        const int s = (gcol >= 1536) ? 2 : (gcol >= 768 ? 1 : 0);
        const int rem2 = gcol - s * 768;
        const int head = rem2 >> 6, hd = rem2 & 63;
        #pragma unroll
        for (int i = 0; i < 4; ++i) {
          const float v = acc[mt][nt][i] + bval;
          const size_t bh = (size_t)(rowW[i] + head);
          if (s == 0)      ((u16*)out0)[(bh * 196 + rowN[i]) * 64 + hd] = f2b(v);
          else if (s == 1) out1[(bh * 196 + rowN[i]) * 64 + hd] = f2b(v * 0.125f); // fold SCALE into K
          else             out2[(bh * 64 + hd) * 224 + rowN[i]] = f2b(v);          // V^T, stride 224
        }
      } else if (EPI == 1) {
        #pragma unroll
        for (int i = 0; i < 4; ++i) {
          const int grow = m0 + wm + mt * 16 + q4 * 4 + i;
          const size_t idx = (size_t)grow * 768 + gcol;
          ((float*)out0)[idx] = acc[mt][nt][i] + bval + extra[idx];
        }
      } else {
        #pragma unroll
        for (int i = 0; i < 4; ++i) {
          const int grow = m0 + wm + mt * 16 + q4 * 4 + i;
          const float v = acc[mt][nt][i] + bval;
          // gelu(v) = v * sigmoid(1.5957691216 v (1 + 0.044715 v^2)); |err|<~4e-4
          const float u2 = v * (1.5957691216f + 0.0713548163f * v * v);
          const float gl = v / (1.0f + __expf(-u2));
          ((u16*)out0)[(size_t)grow * 3072 + gcol] = f2b(gl);
        }
      }
    }
  }
}

// ---------------------------------------------------------------------------
// Windowed attention, one workgroup per (win, head).  N=196 tokens, HD=64.
// Phase 0: rel-pos bias via structure-exploiting MFMA — group q-rows by
// ii (for rel_h) / jj (for rel_w): one 16x16x64 tile per group, 28 tiles
// total -> MhAll/MwAll[196][14] bf16 in LDS.
// Per 32-row chunk: 26 score tiles (bias folded at write) -> no-max softmax
// (unnormalized e bf16, 1/sum folded into PV epilogue) -> PV + raster write.
// Ps (u16, stride 232) aliases the Ss f32 buffer; barrier separates the
// softmax read and write phases.  LDS ~37 KB -> 4 blocks/CU.
// ---------------------------------------------------------------------------
__global__ __launch_bounds__(256)
void attn_kernel(const u16* __restrict__ Qb, const u16* __restrict__ Kb,
                 const u16* __restrict__ Vtb,
                 const u16* __restrict__ RHB, const u16* __restrict__ RWB,
                 u16* __restrict__ outO)
{
  __shared__ __align__(16) float Ss[32 * 201];   // Ps (u16, stride 232) aliases base
  __shared__ u16 MhAll[196 * 14];
  __shared__ u16 MwAll[196 * 14];
  __shared__ float Sinv[32];
  u16* Ps = (u16*)Ss;

  const int tid  = threadIdx.x;
  const int lane = tid & 63;
  const int wave = tid >> 6;
  const int cl = lane & 15;
  const int q4 = lane >> 4;
  const int bh = blockIdx.x;
  const int win = bh / 12, head = bh - win * 12;
  const int bb = win / 25, r25 = win - bb * 25;
  const int wwh = r25 / 5, www = r25 - wwh * 5;

  const u16* Qbh = Qb  + (size_t)bh * 196 * 64;
  const u16* Kbh = Kb  + (size_t)bh * 196 * 64;
  const u16* Vbh = Vtb + (size_t)bh * 64 * 224;

  // ---- Phase 0: MhAll/MwAll via 28 tiles (rel_h grouped by ii, rel_w by jj)
  for (int t = wave; t < 28; t += 4) {
    const int isW = t >= 14;
    const int grp = isW ? t - 14 : t;               // ii (rel_h) or jj (rel_w)
    const int qrow = isW ? cl * 14 + grp : grp * 14 + cl;  // A row cl -> token
    int trow = grp - cl + 13; trow = trow < 0 ? 0 : trow;  // B row cl -> table row
    const u16* TB = isW ? RWB : RHB;
    f32x4 acc = f32x4{0.f, 0.f, 0.f, 0.f};
    #pragma unroll
    for (int ks = 0; ks < 2; ++ks) {
      bf16x8 a  = *(const bf16x8*)(Qbh + (size_t)qrow * 64 + ks * 32 + q4 * 8);
      bf16x8 bv = *(const bf16x8*)(TB + (size_t)trow * 64 + ks * 32 + q4 * 8);
      acc = __builtin_amdgcn_mfma_f32_16x16x32_bf16(a, bv, acc, 0, 0, 0);
    }
    if (cl < 14) {
      #pragma unroll
      for (int i = 0; i < 4; ++i) {
        const int r = q4 * 4 + i;                   // A-row index = group member
        if (r < 14) {
          if (isW) MwAll[(r * 14 + grp) * 14 + cl] = f2b(acc[i]);   // q = r*14+jj
          else     MhAll[(grp * 14 + r) * 14 + cl] = f2b(acc[i]);   // q = ii*14+r
        }
      }
    }
  }
  __syncthreads();

  for (int c = 0; c < 7; ++c) {
    const int qbase = c * 32;
    // hoist this chunk's Q fragments (rows >=196: finite garbage, discarded)
    bf16x8 afr[2][2];
    #pragma unroll
    for (int mt = 0; mt < 2; ++mt)
      #pragma unroll
      for (int ks = 0; ks < 2; ++ks)
        afr[mt][ks] = *(const bf16x8*)(Qbh + (size_t)(qbase + mt * 16 + cl) * 64 + ks * 32 + q4 * 8);

    // ---- score tiles, rel bias folded at write
    for (int t = wave; t < 26; t += 4) {
      const int mt = t / 13, nt = t - mt * 13;
      const int col = nt * 16 + cl;
      f32x4 acc = f32x4{0.f, 0.f, 0.f, 0.f};
      #pragma unroll
      for (int ks = 0; ks < 2; ++ks) {
        bf16x8 bv = *(const bf16x8*)(Kbh + (size_t)col * 64 + ks * 32 + q4 * 8);
        acc = __builtin_amdgcn_mfma_f32_16x16x32_bf16(afr[mt][ks], bv, acc, 0, 0, 0);
      }
      if (col < 196) {
        const int kh = col / 14, kw = col - kh * 14;
        #pragma unroll
        for (int i = 0; i < 4; ++i) {
          const int r = mt * 16 + q4 * 4 + i;
          const int gq = qbase + r;
          float bias = 0.f;
          if (gq < 196) bias = b2f(MhAll[gq * 14 + kh]) + b2f(MwAll[gq * 14 + kw]);
          Ss[r * 201 + col] = acc[i] + bias;
        }
      }
    }
    __syncthreads();                                    // B1: scores visible

    // ---- softmax read: no max-subtraction (|S| bounded), clamp vs garbage rows
    const int r = wave * 8 + (lane >> 3);
    const int s = lane & 7;
    float e[25];
    float sum = 0.f;
    #pragma unroll
    for (int k = 0; k < 25; ++k) {
      const int col = s + 8 * k;
      float ex = 0.f;
      if (col < 196) ex = __expf(fminf(Ss[r * 201 + col], 60.f));
      e[k] = ex;
      sum += ex;
    }
    sum += __shfl_xor(sum, 1);
    sum += __shfl_xor(sum, 2);
    sum += __shfl_xor(sum, 4);
    if (s == 0) Sinv[r] = 1.0f / sum;
    __syncthreads();                                    // B2: Ss reads done, may clobber

    // ---- write unnormalized e as bf16 into Ps (aliases Ss); zero pad cols
    #pragma unroll
    for (int k = 0; k < 25; ++k) {
      const int col = s + 8 * k;                        // <= 199
      Ps[r * 232 + col] = (col < 196) ? f2b(e[k]) : (u16)0;
    }
    for (int z = tid; z < 384; z += 256) {              // cols 200..223 -> 0
      const int rr = z / 12, m = z - rr * 12;
      *(uint32_t*)&Ps[rr * 232 + 200 + 2 * m] = 0;
    }
    __syncthreads();                                    // B3: Ps ready

    // ---- O = P @ V, normalize by Sinv in epilogue; raster write
    {
      const int hd = wave * 16 + cl;
      f32x4 acc0 = f32x4{0.f, 0.f, 0.f, 0.f};
      f32x4 acc1 = f32x4{0.f, 0.f, 0.f, 0.f};
      #pragma unroll
      for (int ks = 0; ks < 7; ++ks) {
        bf16x8 bv = *(const bf16x8*)(Vbh + (size_t)hd * 224 + ks * 32 + q4 * 8);
        bf16x8 a0 = *(const bf16x8*)&Ps[(cl)      * 232 + ks * 32 + q4 * 8];
        bf16x8 a1 = *(const bf16x8*)&Ps[(16 + cl) * 232 + ks * 32 + q4 * 8];
        acc0 = __builtin_amdgcn_mfma_f32_16x16x32_bf16(a0, bv, acc0, 0, 0, 0);
        acc1 = __builtin_amdgcn_mfma_f32_16x16x32_bf16(a1, bv, acc1, 0, 0, 0);
      }
      #pragma unroll
      for (int i = 0; i < 4; ++i) {
        #pragma unroll
        for (int half = 0; half < 2; ++half) {
          const int q = qbase + half * 16 + q4 * 4 + i;
          if (q < 196) {
            const float av = (half ? acc1[i] : acc0[i]) * Sinv[half * 16 + q4 * 4 + i];
            const int ii = q / 14, jj = q - ii * 14;
            const int gh = wwh * 14 + ii, gw = www * 14 + jj;
            if (gh < 64 && gw < 64)
              outO[(((size_t)bb * 64 + gh) * 64 + gw) * 768 + head * 64 + hd] = f2b(av);
          }
        }
      }
    }
    __syncthreads();                                    // B4: Ps consumed
  }
}

// ---------------------------------------------------------------------------
extern "C" void kernel_launch(void* const* d_in, const int* in_sizes, int n_in,
                              void* d_out, int out_size, void* d_ws, size_t ws_size,
                              hipStream_t stream)
{
  (void)in_sizes; (void)n_in; (void)out_size; (void)ws_size;
  const float* x      = (const float*)d_in[0];
  const float* ln1_g  = (const float*)d_in[1];
  const float* ln1_b  = (const float*)d_in[2];
  const float* qkv_w  = (const float*)d_in[3];
  const float* qkv_b  = (const float*)d_in[4];
  const float* proj_w = (const float*)d_in[5];
  const float* proj_b = (const float*)d_in[6];
  const float* rph    = (const float*)d_in[7];
  const float* rpw    = (const float*)d_in[8];
  const float* ln2_g  = (const float*)d_in[9];
  const float* ln2_b  = (const float*)d_in[10];
  const float* lin1_w = (const float*)d_in[11];
  const float* lin1_b = (const float*)d_in[12];
  const float* lin2_w = (const float*)d_in[13];
  const float* lin2_b = (const float*)d_in[14];
  float* outF = (float*)d_out;

  char* ws = (char*)d_ws;
  size_t off = 0;
  auto allocB = [&](size_t bytes) -> char* {
    char* p = ws + off;
    off += (bytes + 255) & ~(size_t)255;
    return p;
  };
  u16* qkvT  = (u16*)allocB((size_t)2304 * 768 * 2);
  u16* projT = (u16*)allocB((size_t)768 * 768 * 2);
  u16* lin1T = (u16*)allocB((size_t)3072 * 768 * 2);
  u16* lin2T = (u16*)allocB((size_t)768 * 3072 * 2);
  u16* RHB   = (u16*)allocB((size_t)(27 * 64 + 64) * 2);
  u16* RWB   = (u16*)allocB((size_t)(27 * 64 + 64) * 2);
  u16* xn    = (u16*)allocB((size_t)32768 * 768 * 2);   // ln1-out -> attnO -> ln2-out
  char* region = allocB((size_t)201326592);             // Q|K|Vt, later hbuf+mid
  u16* Qb   = (u16*)region;                             // 30,105,600 elems
  u16* Kb   = Qb + (size_t)30105600;                    // 30,105,600 elems
  u16* Vtb  = Kb + (size_t)30105600;                    // 34,406,400 elems (2400*64*224)
  float* hbuf = (float*)region;                         // 32768*768 fp32 = 100,663,296 B
  u16* midQ = (u16*)(region + (size_t)100663296);       // 16384*3072 bf16 = 100,663,296 B
  // lifetimes: Q/K/V dead before proj writes hbuf; hbuf/midQ disjoint ranges.

  dim3 blk(256);
  transpose_w<<<dim3(72, 24), blk, 0, stream>>>(qkv_w,  qkvT, 768, 2304);
  transpose_w<<<dim3(24, 24), blk, 0, stream>>>(proj_w, projT, 768, 768);
  transpose_w<<<dim3(96, 24), blk, 0, stream>>>(lin1_w, lin1T, 768, 3072);
  transpose_w<<<dim3(24, 96), blk, 0, stream>>>(lin2_w, lin2T, 3072, 768);
  rel_cast<<<7, blk, 0, stream>>>(rph, rpw, RHB, RWB);

  // LN1 (raster rows) -> xn bf16
  ln_f32<<<8192, blk, 0, stream>>>(x, ln1_g, ln1_b, xn);

  // QKV projection, raster M, scatter epilogue (K pre-scaled, V^T stride 224)
  gemm_bt<0><<<dim3(256, 18), blk, 0, stream>>>(xn, qkvT, 32768, 2304, 768,
                                                qkv_b, Qb, Kb, Vtb, nullptr);
  // pad-token rows of Q/K/V = bias exactly
  qkv_padfill<<<9800, blk, 0, stream>>>(qkv_b, Qb, Kb, Vtb);

  // windowed attention -> attnO (= xn, raster, bf16)
  attn_kernel<<<2400, blk, 0, stream>>>(Qb, Kb, Vtb, RHB, RWB, xn);

  // proj + residual(x) -> hbuf fp32
  gemm_bt<1><<<dim3(256, 6), blk, 0, stream>>>(xn, projT, 32768, 768, 768,
                                               proj_b, hbuf, nullptr, nullptr, x);

  // LN2 -> xn bf16
  ln_f32<<<8192, blk, 0, stream>>>(hbuf, ln2_g, ln2_b, xn);

  // MLP in 2 M-passes of 16384 rows (mid half fits beside hbuf);
  // mlp2 grid 768 blocks (3/CU) vs 384 at 4-pass — occupancy fix.
  for (int pass = 0; pass < 2; ++pass) {
    const size_t ro = (size_t)pass * 16384;
    gemm_bt<2><<<dim3(128, 24), blk, 0, stream>>>(xn + ro * 768, lin1T, 16384, 3072, 768,
                                                  lin1_b, midQ, nullptr, nullptr, nullptr);
    gemm_bt<1><<<dim3(128, 6), blk, 0, stream>>>(midQ, lin2T, 16384, 768, 3072,
                                                 lin2_b, outF + ro * 768, nullptr, nullptr,
                                                 hbuf + ro * 768);
  }
}

// Round 6
// 1271.920 us; speedup vs baseline: 1.5097x; 1.1560x over previous
//
#include <hip/hip_runtime.h>
#include <hip/hip_bf16.h>
#include <math.h>
#include <stdint.h>

typedef unsigned short u16;
typedef __attribute__((ext_vector_type(8))) short bf16x8;
typedef __attribute__((ext_vector_type(4))) float f32x4;

__device__ __forceinline__ float b2f(u16 u) {
  union { float f; uint32_t i; } v; v.i = ((uint32_t)u) << 16; return v.f;
}
__device__ __forceinline__ u16 f2b(float f) {
  union { float f; uint32_t i; } v; v.f = f;
  uint32_t x = v.i;
  return (u16)((x + 0x7fffu + ((x >> 16) & 1u)) >> 16);
}

// async global->LDS, 16B per lane; LDS dest must be wave-uniform base + lane*16
__device__ __forceinline__ void gl_lds16(const u16* g, u16* l) {
  __builtin_amdgcn_global_load_lds(
      (const __attribute__((address_space(1))) void*)g,
      (__attribute__((address_space(3))) void*)l, 16, 0, 0);
}

// ---------------------------------------------------------------------------
// Weight transpose + fp32->bf16: in fp32 [K][N] -> out bf16 [N][K].
// ---------------------------------------------------------------------------
__global__ __launch_bounds__(256)
void transpose_w(const float* __restrict__ in, u16* __restrict__ out, int K, int N) {
  __shared__ float t[32][33];
  const int x = threadIdx.x & 31;
  const int y = threadIdx.x >> 5;         // 0..7
  const int n0 = blockIdx.x * 32;
  const int k0 = blockIdx.y * 32;
  #pragma unroll
  for (int yy = 0; yy < 32; yy += 8)
    t[y + yy][x] = in[(size_t)(k0 + y + yy) * N + n0 + x];
  __syncthreads();
  #pragma unroll
  for (int yy = 0; yy < 32; yy += 8)
    out[(size_t)(n0 + y + yy) * K + k0 + x] = f2b(t[x][y + yy]);
}

// ---------------------------------------------------------------------------
// Cast rel-pos tables fp32[27][64] -> bf16.
// ---------------------------------------------------------------------------
__global__ __launch_bounds__(256)
void rel_cast(const float* __restrict__ rph, const float* __restrict__ rpw,
              u16* __restrict__ RHB, u16* __restrict__ RWB)
{
  const int i = blockIdx.x * 256 + threadIdx.x;
  if (i < 27 * 64) { RHB[i] = f2b(rph[i]); RWB[i] = f2b(rpw[i]); }
}

// ---------------------------------------------------------------------------
// LayerNorm over C=768 (fp32 in, bf16 out), one wave per row, raster rows.
// ---------------------------------------------------------------------------
__global__ __launch_bounds__(256)
void ln_f32(const float* __restrict__ xin, const float* __restrict__ g,
            const float* __restrict__ b, u16* __restrict__ out)
{
  const int R = blockIdx.x * 4 + (threadIdx.x >> 6);   // 0..32767
  const int lane = threadIdx.x & 63;
  const float* p = xin + (size_t)R * 768 + lane * 12;
  float v[12];
  float4 a0 = *(const float4*)(p);
  float4 a1 = *(const float4*)(p + 4);
  float4 a2 = *(const float4*)(p + 8);
  v[0]=a0.x; v[1]=a0.y; v[2]=a0.z;  v[3]=a0.w;
  v[4]=a1.x; v[5]=a1.y; v[6]=a1.z;  v[7]=a1.w;
  v[8]=a2.x; v[9]=a2.y; v[10]=a2.z; v[11]=a2.w;
  float sum = 0.f, sq = 0.f;
  #pragma unroll
  for (int i = 0; i < 12; ++i) { sum += v[i]; sq += v[i] * v[i]; }
  #pragma unroll
  for (int m = 1; m < 64; m <<= 1) { sum += __shfl_xor(sum, m); sq += __shfl_xor(sq, m); }
  const float mu  = sum * (1.0f / 768.0f);
  const float var = sq * (1.0f / 768.0f) - mu * mu;
  const float rs  = rsqrtf(var + 1e-6f);
  u16 o[12];
  #pragma unroll
  for (int i = 0; i < 12; ++i)
    o[i] = f2b((v[i] - mu) * rs * g[lane * 12 + i] + b[lane * 12 + i]);
  u16* q = out + (size_t)R * 768 + lane * 12;
  *(ushort4*)(q)     = make_ushort4(o[0], o[1], o[2],  o[3]);
  *(ushort4*)(q + 4) = make_ushort4(o[4], o[5], o[6],  o[7]);
  *(ushort4*)(q + 8) = make_ushort4(o[8], o[9], o[10], o[11]);
}

// ---------------------------------------------------------------------------
// Pad-row fill for Q/K/V^T: padded window tokens (gh>=64 || gw>=64) have
// h==0 after the reference's post-LN zero-pad, so qkv = bias exactly.
// ---------------------------------------------------------------------------
__global__ __launch_bounds__(256)
void qkv_padfill(const float* __restrict__ qkv_b,
                 u16* __restrict__ Qb, u16* __restrict__ Kb, u16* __restrict__ Vtb)
{
  const int R = blockIdx.x * 4 + (threadIdx.x >> 6);   // 0..39199 = win*196+n
  const int lane = threadIdx.x & 63;
  const int win = R / 196, n = R - win * 196;
  const int r25 = win % 25;
  const int wh = r25 / 5, ww = r25 - wh * 5;
  const int ii = n / 14,  jj = n - ii * 14;
  const int gh = wh * 14 + ii, gw = ww * 14 + jj;
  if (gh < 64 && gw < 64) return;   // interior handled by the QKV GEMM
  #pragma unroll
  for (int head = 0; head < 12; ++head) {
    const size_t bh = (size_t)(win * 12 + head);
    Qb[(bh * 196 + n) * 64 + lane]  = f2b(qkv_b[head * 64 + lane]);
    Kb[(bh * 196 + n) * 64 + lane]  = f2b(qkv_b[768 + head * 64 + lane] * 0.125f);
    Vtb[(bh * 64 + lane) * 224 + n] = f2b(qkv_b[1536 + head * 64 + lane]);
  }
}

// ---------------------------------------------------------------------------
// GEMM: C[M,N] = A[M,K] @ B[K,N] (+fp32 bias, fused epilogue).  A,BT bf16.
// 128x128 tile, BK=32, 256 thr = 4 waves, each wave 64x64 via 4x4 tiles of
// mfma_f32_16x16x32_bf16.
// T4 counted-vmcnt pipeline: 3 LDS K-tile buffers (48 KB); stage tile t+2
// while computing tile t; per tile ONE raw s_barrier + s_waitcnt vmcnt(4)
// (tile t's 4 global_load_lds done, tile t+1's 4 stay in flight — never
// drain to 0 in the loop).  Buffer-reuse safety: stage(t+2) writes
// buf((t-1)%3); all waves' ds_reads of tile t-1 completed before the
// barrier that precedes the stage issue.
// XCD-chunk swizzle: each XCD sweeps a contiguous m-range, n fastest
// (nwg % 8 == 0 for all launches).
// Stores are PLAIN (r4: nt stores caused 3.6x write amplification on the
// scattered epilogues); EPI1 residual reads are nontemporal (streamed).
// EPI: 0 = QKV scatter (out0=Q bf16, out1=K*0.125 bf16, out2=V^T bf16 s224)
//      1 = +bias, +extra(fp32 residual) -> fp32 out0   (proj & mlp2)
//      2 = +bias, sigmoid-form GELU -> bf16 out0 [M,3072]  (mlp1)
// M multiple of 128, K multiple of 32, K/32 >= 3 (all launches comply).
// ---------------------------------------------------------------------------
template<int EPI>
__global__ __launch_bounds__(256)
void gemm_bt(const u16* __restrict__ A, const u16* __restrict__ BT,
             int M, int N, int K,
             const float* __restrict__ bias,
             void* __restrict__ out0, u16* __restrict__ out1, u16* __restrict__ out2,
             const float* __restrict__ extra)
{
  __shared__ __align__(16) u16 As3[3 * 4096];   // 3 bufs x 128x32
  __shared__ __align__(16) u16 Bs3[3 * 4096];
  const int tid  = threadIdx.x;
  const int lane = tid & 63;
  const int wave = tid >> 6;

  // XCD-chunk swizzle (bijective; nwg % 8 == 0 for every launch)
  const int nwg = gridDim.x * gridDim.y;
  const int lid = blockIdx.y * gridDim.x + blockIdx.x;   // dispatch-linear (x fastest)
  const int nl  = (lid & 7) * (nwg >> 3) + (lid >> 3);
  const int bx  = nl / gridDim.y;          // m-tile
  const int by  = nl - bx * gridDim.y;     // n-tile (fastest within an XCD chunk)
  const int m0 = bx * 128;
  const int n0 = by * 128;

  const int wm = (wave >> 1) << 6;
  const int wn = (wave & 1) << 6;
  const int cl = lane & 15;
  const int q4 = lane >> 4;

  f32x4 acc[4][4];
  #pragma unroll
  for (int i = 0; i < 4; ++i)
    #pragma unroll
    for (int j = 0; j < 4; ++j) acc[i][j] = f32x4{0.f, 0.f, 0.f, 0.f};

  const int sr = tid >> 2;            // 0..63
  const int sk = (tid & 3) << 3;      // 0,8,16,24
  const u16* ag0 = A  + (size_t)(m0 + sr) * K + sk;
  const u16* ag1 = A  + (size_t)(m0 + 64 + sr) * K + sk;
  const u16* bg0 = BT + (size_t)(n0 + sr) * K + sk;
  const u16* bg1 = BT + (size_t)(n0 + 64 + sr) * K + sk;

  const int nt = K >> 5;

  auto STAGE = [&](int buf, int k0) {
    u16* as = As3 + buf * 4096;
    u16* bs = Bs3 + buf * 4096;
    gl_lds16(ag0 + k0, &as[tid * 8]);
    gl_lds16(ag1 + k0, &as[tid * 8 + 2048]);
    gl_lds16(bg0 + k0, &bs[tid * 8]);
    gl_lds16(bg1 + k0, &bs[tid * 8 + 2048]);
  };
  auto COMPUTE = [&](int buf) {
    const u16* as = As3 + buf * 4096;
    const u16* bs = Bs3 + buf * 4096;
    bf16x8 af[4], bfv[4];
    #pragma unroll
    for (int i = 0; i < 4; ++i) af[i]  = *(const bf16x8*)&as[(wm + i * 16 + cl) * 32 + q4 * 8];
    #pragma unroll
    for (int i = 0; i < 4; ++i) bfv[i] = *(const bf16x8*)&bs[(wn + i * 16 + cl) * 32 + q4 * 8];
    #pragma unroll
    for (int i = 0; i < 4; ++i)
      #pragma unroll
      for (int j = 0; j < 4; ++j)
        acc[i][j] = __builtin_amdgcn_mfma_f32_16x16x32_bf16(af[i], bfv[j], acc[i][j], 0, 0, 0);
  };

  // prologue: stage tiles 0 and 1
  STAGE(0, 0);
  STAGE(1, 32);

  int bufc = 0;                       // buffer holding tile t
  for (int t = 0; t < nt - 1; ++t) {
    asm volatile("s_waitcnt vmcnt(4)" ::: "memory");   // tile t landed; t+1 in flight
    __builtin_amdgcn_s_barrier();
    __builtin_amdgcn_sched_barrier(0);
    if (t + 2 < nt) {
      const int nb = (bufc + 2 >= 3) ? bufc - 1 : bufc + 2;   // (t+2)%3
      STAGE(nb, (t + 2) << 5);
    }
    COMPUTE(bufc);
    bufc = (bufc + 1 == 3) ? 0 : bufc + 1;
  }
  // peeled last tile: drain
  asm volatile("s_waitcnt vmcnt(0)" ::: "memory");
  __builtin_amdgcn_s_barrier();
  __builtin_amdgcn_sched_barrier(0);
  COMPUTE(bufc);

  #pragma unroll
  for (int mt = 0; mt < 4; ++mt) {
    int rowW[4], rowN[4];
    if (EPI == 0) {
      // hoist raster->window mapping out of the nt loop (depends on grow only)
      #pragma unroll
      for (int i = 0; i < 4; ++i) {
        const int grow = m0 + wm + mt * 16 + q4 * 4 + i;
        const int bb = grow >> 12, rem = grow & 4095;
        const int gh = rem >> 6, gw = rem & 63;
        const int wh = gh / 14, ii = gh - wh * 14;
        const int ww = gw / 14, jj = gw - ww * 14;
        rowW[i] = (bb * 25 + wh * 5 + ww) * 12;   // win*12
        rowN[i] = ii * 14 + jj;                   // n
      }
    }
    #pragma unroll
    for (int nt2 = 0; nt2 < 4; ++nt2) {
      const int gcol = n0 + wn + nt2 * 16 + cl;
      const float bval = bias[gcol];
      if (EPI == 0) {
        const int s = (gcol >= 1536) ? 2 : (gcol >= 768 ? 1 : 0);
        const int rem2 = gcol - s * 768;
        const int head = rem2 >> 6, hd = rem2 & 63;
        #pragma unroll
        for (int i = 0; i < 4; ++i) {
          const float v = acc[mt][nt2][i] + bval;
          const size_t bh = (size_t)(rowW[i] + head);
          if (s == 0)      ((u16*)out0)[(bh * 196 + rowN[i]) * 64 + hd] = f2b(v);
          else if (s == 1) out1[(bh * 196 + rowN[i]) * 64 + hd] = f2b(v * 0.125f); // fold SCALE into K
          else             out2[(bh * 64 + hd) * 224 + rowN[i]] = f2b(v);          // V^T, stride 224
        }
      } else if (EPI == 1) {
        #pragma unroll
        for (int i = 0; i < 4; ++i) {
          const int grow = m0 + wm + mt * 16 + q4 * 4 + i;
          const size_t idx = (size_t)grow * 768 + gcol;
          const float ex = __builtin_nontemporal_load(&extra[idx]);
          ((float*)out0)[idx] = acc[mt][nt2][i] + bval + ex;
        }
      } else {
        #pragma unroll
        for (int i = 0; i < 4; ++i) {
          const int grow = m0 + wm + mt * 16 + q4 * 4 + i;
          const float v = acc[mt][nt2][i] + bval;
          // gelu(v) = v * sigmoid(1.5957691216 v (1 + 0.044715 v^2)); |err|<~4e-4
          const float u2 = v * (1.5957691216f + 0.0713548163f * v * v);
          const float gl = v / (1.0f + __expf(-u2));
          ((u16*)out0)[(size_t)grow * 3072 + gcol] = f2b(gl);
        }
      }
    }
  }
}

// ---------------------------------------------------------------------------
// Windowed attention, one workgroup per (win, head).  N=196 tokens, HD=64.
// Phase 0: rel-pos bias via structure-exploiting MFMA — group q-rows by
// ii (for rel_h) / jj (for rel_w): one 16x16x64 tile per group, 28 tiles
// total -> MhAll/MwAll[196][14] bf16 in LDS.
// Per 32-row chunk: 26 score tiles (bias folded at write) -> no-max softmax
// (unnormalized e bf16, 1/sum folded into PV epilogue) -> PV + raster write.
// Ps (u16, stride 232) aliases the Ss f32 buffer; barrier separates the
// softmax read and write phases.  LDS ~37 KB -> 4 blocks/CU.
// ---------------------------------------------------------------------------
__global__ __launch_bounds__(256)
void attn_kernel(const u16* __restrict__ Qb, const u16* __restrict__ Kb,
                 const u16* __restrict__ Vtb,
                 const u16* __restrict__ RHB, const u16* __restrict__ RWB,
                 u16* __restrict__ outO)
{
  __shared__ __align__(16) float Ss[32 * 201];   // Ps (u16, stride 232) aliases base
  __shared__ u16 MhAll[196 * 14];
  __shared__ u16 MwAll[196 * 14];
  __shared__ float Sinv[32];
  u16* Ps = (u16*)Ss;

  const int tid  = threadIdx.x;
  const int lane = tid & 63;
  const int wave = tid >> 6;
  const int cl = lane & 15;
  const int q4 = lane >> 4;
  const int bh = blockIdx.x;
  const int win = bh / 12, head = bh - win * 12;
  const int bb = win / 25, r25 = win - bb * 25;
  const int wwh = r25 / 5, www = r25 - wwh * 5;

  const u16* Qbh = Qb  + (size_t)bh * 196 * 64;
  const u16* Kbh = Kb  + (size_t)bh * 196 * 64;
  const u16* Vbh = Vtb + (size_t)bh * 64 * 224;

  // ---- Phase 0: MhAll/MwAll via 28 tiles (rel_h grouped by ii, rel_w by jj)
  for (int t = wave; t < 28; t += 4) {
    const int isW = t >= 14;
    const int grp = isW ? t - 14 : t;               // ii (rel_h) or jj (rel_w)
    const int qrow = isW ? cl * 14 + grp : grp * 14 + cl;  // A row cl -> token
    int trow = grp - cl + 13; trow = trow < 0 ? 0 : trow;  // B row cl -> table row
    const u16* TB = isW ? RWB : RHB;
    f32x4 acc = f32x4{0.f, 0.f, 0.f, 0.f};
    #pragma unroll
    for (int ks = 0; ks < 2; ++ks) {
      bf16x8 a  = *(const bf16x8*)(Qbh + (size_t)qrow * 64 + ks * 32 + q4 * 8);
      bf16x8 bv = *(const bf16x8*)(TB + (size_t)trow * 64 + ks * 32 + q4 * 8);
      acc = __builtin_amdgcn_mfma_f32_16x16x32_bf16(a, bv, acc, 0, 0, 0);
    }
    if (cl < 14) {
      #pragma unroll
      for (int i = 0; i < 4; ++i) {
        const int r = q4 * 4 + i;                   // A-row index = group member
        if (r < 14) {
          if (isW) MwAll[(r * 14 + grp) * 14 + cl] = f2b(acc[i]);   // q = r*14+jj
          else     MhAll[(grp * 14 + r) * 14 + cl] = f2b(acc[i]);   // q = ii*14+r
        }
      }
    }
  }
  __syncthreads();

  for (int c = 0; c < 7; ++c) {
    const int qbase = c * 32;
    // hoist this chunk's Q fragments (rows >=196: finite garbage, discarded)
    bf16x8 afr[2][2];
    #pragma unroll
    for (int mt = 0; mt < 2; ++mt)
      #pragma unroll
      for (int ks = 0; ks < 2; ++ks)
        afr[mt][ks] = *(const bf16x8*)(Qbh + (size_t)(qbase + mt * 16 + cl) * 64 + ks * 32 + q4 * 8);

    // ---- score tiles, rel bias folded at write
    for (int t = wave; t < 26; t += 4) {
      const int mt = t / 13, nt = t - mt * 13;
      const int col = nt * 16 + cl;
      f32x4 acc = f32x4{0.f, 0.f, 0.f, 0.f};
      #pragma unroll
      for (int ks = 0; ks < 2; ++ks) {
        bf16x8 bv = *(const bf16x8*)(Kbh + (size_t)col * 64 + ks * 32 + q4 * 8);
        acc = __builtin_amdgcn_mfma_f32_16x16x32_bf16(afr[mt][ks], bv, acc, 0, 0, 0);
      }
      if (col < 196) {
        const int kh = col / 14, kw = col - kh * 14;
        #pragma unroll
        for (int i = 0; i < 4; ++i) {
          const int r = mt * 16 + q4 * 4 + i;
          const int gq = qbase + r;
          float bias = 0.f;
          if (gq < 196) bias = b2f(MhAll[gq * 14 + kh]) + b2f(MwAll[gq * 14 + kw]);
          Ss[r * 201 + col] = acc[i] + bias;
        }
      }
    }
    __syncthreads();                                    // B1: scores visible

    // ---- softmax read: no max-subtraction (|S| bounded), clamp vs garbage rows
    const int r = wave * 8 + (lane >> 3);
    const int s = lane & 7;
    float e[25];
    float sum = 0.f;
    #pragma unroll
    for (int k = 0; k < 25; ++k) {
      const int col = s + 8 * k;
      float ex = 0.f;
      if (col < 196) ex = __expf(fminf(Ss[r * 201 + col], 60.f));
      e[k] = ex;
      sum += ex;
    }
    sum += __shfl_xor(sum, 1);
    sum += __shfl_xor(sum, 2);
    sum += __shfl_xor(sum, 4);
    if (s == 0) Sinv[r] = 1.0f / sum;
    __syncthreads();                                    // B2: Ss reads done, may clobber

    // ---- write unnormalized e as bf16 into Ps (aliases Ss); zero pad cols
    #pragma unroll
    for (int k = 0; k < 25; ++k) {
      const int col = s + 8 * k;                        // <= 199
      Ps[r * 232 + col] = (col < 196) ? f2b(e[k]) : (u16)0;
    }
    for (int z = tid; z < 384; z += 256) {              // cols 200..223 -> 0
      const int rr = z / 12, m = z - rr * 12;
      *(uint32_t*)&Ps[rr * 232 + 200 + 2 * m] = 0;
    }
    __syncthreads();                                    // B3: Ps ready

    // ---- O = P @ V, normalize by Sinv in epilogue; raster write
    {
      const int hd = wave * 16 + cl;
      f32x4 acc0 = f32x4{0.f, 0.f, 0.f, 0.f};
      f32x4 acc1 = f32x4{0.f, 0.f, 0.f, 0.f};
      #pragma unroll
      for (int ks = 0; ks < 7; ++ks) {
        bf16x8 bv = *(const bf16x8*)(Vbh + (size_t)hd * 224 + ks * 32 + q4 * 8);
        bf16x8 a0 = *(const bf16x8*)&Ps[(cl)      * 232 + ks * 32 + q4 * 8];
        bf16x8 a1 = *(const bf16x8*)&Ps[(16 + cl) * 232 + ks * 32 + q4 * 8];
        acc0 = __builtin_amdgcn_mfma_f32_16x16x32_bf16(a0, bv, acc0, 0, 0, 0);
        acc1 = __builtin_amdgcn_mfma_f32_16x16x32_bf16(a1, bv, acc1, 0, 0, 0);
      }
      #pragma unroll
      for (int i = 0; i < 4; ++i) {
        #pragma unroll
        for (int half = 0; half < 2; ++half) {
          const int q = qbase + half * 16 + q4 * 4 + i;
          if (q < 196) {
            const float av = (half ? acc1[i] : acc0[i]) * Sinv[half * 16 + q4 * 4 + i];
            const int ii = q / 14, jj = q - ii * 14;
            const int gh = wwh * 14 + ii, gw = www * 14 + jj;
            if (gh < 64 && gw < 64)
              outO[(((size_t)bb * 64 + gh) * 64 + gw) * 768 + head * 64 + hd] = f2b(av);
          }
        }
      }
    }
    __syncthreads();                                    // B4: Ps consumed
  }
}

// ---------------------------------------------------------------------------
extern "C" void kernel_launch(void* const* d_in, const int* in_sizes, int n_in,
                              void* d_out, int out_size, void* d_ws, size_t ws_size,
                              hipStream_t stream)
{
  (void)in_sizes; (void)n_in; (void)out_size; (void)ws_size;
  const float* x      = (const float*)d_in[0];
  const float* ln1_g  = (const float*)d_in[1];
  const float* ln1_b  = (const float*)d_in[2];
  const float* qkv_w  = (const float*)d_in[3];
  const float* qkv_b  = (const float*)d_in[4];
  const float* proj_w = (const float*)d_in[5];
  const float* proj_b = (const float*)d_in[6];
  const float* rph    = (const float*)d_in[7];
  const float* rpw    = (const float*)d_in[8];
  const float* ln2_g  = (const float*)d_in[9];
  const float* ln2_b  = (const float*)d_in[10];
  const float* lin1_w = (const float*)d_in[11];
  const float* lin1_b = (const float*)d_in[12];
  const float* lin2_w = (const float*)d_in[13];
  const float* lin2_b = (const float*)d_in[14];
  float* outF = (float*)d_out;

  char* ws = (char*)d_ws;
  size_t off = 0;
  auto allocB = [&](size_t bytes) -> char* {
    char* p = ws + off;
    off += (bytes + 255) & ~(size_t)255;
    return p;
  };
  u16* qkvT  = (u16*)allocB((size_t)2304 * 768 * 2);
  u16* projT = (u16*)allocB((size_t)768 * 768 * 2);
  u16* lin1T = (u16*)allocB((size_t)3072 * 768 * 2);
  u16* lin2T = (u16*)allocB((size_t)768 * 3072 * 2);
  u16* RHB   = (u16*)allocB((size_t)(27 * 64 + 64) * 2);
  u16* RWB   = (u16*)allocB((size_t)(27 * 64 + 64) * 2);
  u16* xn    = (u16*)allocB((size_t)32768 * 768 * 2);   // ln1-out -> attnO -> ln2-out
  char* region = allocB((size_t)201326592);             // Q|K|Vt, later hbuf+mid
  u16* Qb   = (u16*)region;                             // 30,105,600 elems
  u16* Kb   = Qb + (size_t)30105600;                    // 30,105,600 elems
  u16* Vtb  = Kb + (size_t)30105600;                    // 34,406,400 elems (2400*64*224)
  float* hbuf = (float*)region;                         // 32768*768 fp32 = 100,663,296 B
  u16* midQ = (u16*)(region + (size_t)100663296);       // 16384*3072 bf16 = 100,663,296 B
  // lifetimes: Q/K/V dead before proj writes hbuf; hbuf/midQ disjoint ranges.

  dim3 blk(256);
  transpose_w<<<dim3(72, 24), blk, 0, stream>>>(qkv_w,  qkvT, 768, 2304);
  transpose_w<<<dim3(24, 24), blk, 0, stream>>>(proj_w, projT, 768, 768);
  transpose_w<<<dim3(96, 24), blk, 0, stream>>>(lin1_w, lin1T, 768, 3072);
  transpose_w<<<dim3(24, 96), blk, 0, stream>>>(lin2_w, lin2T, 3072, 768);
  rel_cast<<<7, blk, 0, stream>>>(rph, rpw, RHB, RWB);

  // LN1 (raster rows) -> xn bf16
  ln_f32<<<8192, blk, 0, stream>>>(x, ln1_g, ln1_b, xn);

  // QKV projection, raster M, scatter epilogue (K pre-scaled, V^T stride 224)
  gemm_bt<0><<<dim3(256, 18), blk, 0, stream>>>(xn, qkvT, 32768, 2304, 768,
                                                qkv_b, Qb, Kb, Vtb, nullptr);
  // pad-token rows of Q/K/V = bias exactly
  qkv_padfill<<<9800, blk, 0, stream>>>(qkv_b, Qb, Kb, Vtb);

  // windowed attention -> attnO (= xn, raster, bf16)
  attn_kernel<<<2400, blk, 0, stream>>>(Qb, Kb, Vtb, RHB, RWB, xn);

  // proj + residual(x) -> hbuf fp32
  gemm_bt<1><<<dim3(256, 6), blk, 0, stream>>>(xn, projT, 32768, 768, 768,
                                               proj_b, hbuf, nullptr, nullptr, x);

  // LN2 -> xn bf16
  ln_f32<<<8192, blk, 0, stream>>>(hbuf, ln2_g, ln2_b, xn);

  // MLP in 2 M-passes of 16384 rows (mid half fits beside hbuf)
  for (int pass = 0; pass < 2; ++pass) {
    const size_t ro = (size_t)pass * 16384;
    gemm_bt<2><<<dim3(128, 24), blk, 0, stream>>>(xn + ro * 768, lin1T, 16384, 3072, 768,
                                                  lin1_b, midQ, nullptr, nullptr, nullptr);
    gemm_bt<1><<<dim3(128, 6), blk, 0, stream>>>(midQ, lin2T, 16384, 768, 3072,
                                                 lin2_b, outF + ro * 768, nullptr, nullptr,
                                                 hbuf + ro * 768);
  }
}